// Round 9
// baseline (291.092 us; speedup 1.0000x reference)
//
#include <hip/hip_runtime.h>

// Problem shape (fixed by setup_inputs): B=4, N=16384, M=4096, C=64, K=32
static constexpr int Bn = 4;
static constexpr int Nn = 16384;
static constexpr int Mn = 4096;
static constexpr int Cn = 64;
static constexpr int Kn = 32;

static constexpr int CHUNK   = 2048;
static constexpr int WPB     = 8;            // waves per block
static constexpr int QPW     = 2;            // queries per wave
static constexpr int THREADS = WPB * 64;     // 512
static constexpr int NCHUNK  = Nn / CHUNK;   // 8
static constexpr int NGROUP  = CHUNK / 256;  // 8

// Surrogate-filter margin (dist^2 scale). Worst-case rounding divergence
// between surrogate (yy-2s) and reference dist is ~4e-5; 4e-3 = 100x margin.
static constexpr float EPS = 4e-3f;

typedef unsigned long long ull;
typedef unsigned int u32;

// lane i-1 -> lane i (lane 0 keeps old). DPP wave_shr:1 — VALU pipe, no DS.
__device__ __forceinline__ u32 dpp_shr1(u32 v) {
  return (u32)__builtin_amdgcn_update_dpp((int)v, (int)v, 0x138, 0xf, 0xf, false);
}
__device__ __forceinline__ u32 rdlane(u32 v, int l) {
  return (u32)__builtin_amdgcn_readlane((int)v, l);
}

// async global->LDS, 16B per lane; LDS dest = uniform base + lane*16
__device__ __forceinline__ void gl_lds16(const float* g, float* l) {
  __builtin_amdgcn_global_load_lds(
      (const __attribute__((address_space(1))) void*)g,
      (__attribute__((address_space(3))) void*)l, 16, 0, 0);
}

// full-wave bitonic sort, ascending across 64 lanes (64-bit keys; one-time)
__device__ __forceinline__ ull sort64_asc(ull key, int lane) {
#pragma unroll
  for (int k = 2; k <= 64; k <<= 1) {
#pragma unroll
    for (int j = k >> 1; j > 0; j >>= 1) {
      const ull other = __shfl_xor(key, j);
      const bool keep_min = ((lane & j) == 0) == ((lane & k) == 0);
      const bool take = keep_min ? (other < key) : (other > key);
      key = take ? other : key;
    }
  }
  return key;
}

// Insert one key (kd=dist bits SGPR, ki=idx SGPR) into sorted-by-dist list.
// Tie policy: insertion AFTER the equal-dist run + strict-< admission at the
// call site == lexicographic (dist, idx) order given monotone idx arrival.
__device__ __forceinline__ void insert_one(u32 kd, u32 ki,
                                           u32& lst_d, u32& lst_i,
                                           u32& tau_d, int lane) {
  const int pos = (int)__popcll(__ballot(lst_d <= kd));  // lanes>=32 hold MAX
  const u32 shd = dpp_shr1(lst_d);
  const u32 shi = dpp_shr1(lst_i);
  u32 nd = (lane == pos) ? kd : shd;
  u32 ni = (lane == pos) ? ki : shi;
  nd = (lane < pos) ? lst_d : nd;
  ni = (lane < pos) ? lst_i : ni;
  if (lane < 32) { lst_d = nd; lst_i = ni; }
  tau_d = rdlane(lst_d, 31);
}

// Unified in-idx-order insert over a 256-point group. mAny = lanes whose
// 4-point surrogate max passed. Processing lane-major (ctz order) then j
// keeps global idx order = 4*lane + j ascending.
__device__ __forceinline__ void insert_grp(ull mAny, u32 d0, u32 d1, u32 d2,
                                           u32 d3, u32 sb,
                                           u32& lst_d, u32& lst_i,
                                           u32& tau_d, int lane) {
  while (mAny) {
    const int src = (int)__builtin_ctzll(mAny);
    mAny &= mAny - 1;
    const u32 ib = sb + ((u32)src << 2);
    u32 kd;
    kd = rdlane(d0, src); if (kd < tau_d) insert_one(kd, ib + 0u, lst_d, lst_i, tau_d, lane);
    kd = rdlane(d1, src); if (kd < tau_d) insert_one(kd, ib + 1u, lst_d, lst_i, tau_d, lane);
    kd = rdlane(d2, src); if (kd < tau_d) insert_one(kd, ib + 2u, lst_d, lst_i, tau_d, lane);
    kd = rdlane(d3, src); if (kd < tau_d) insert_one(kd, ib + 3u, lst_d, lst_i, tau_d, lane);
  }
}

__device__ __forceinline__ float tf_of(u32 tau_d, float yyq) {
  return (tau_d == 0xFFFFFFFFu) ? -__builtin_inff()
                                : (yyq - __uint_as_float(tau_d) - EPS) * 0.5f;
}

// ---------------- kernel 0: F [B,C,N] -> FT [B,N,C] ----------------
__global__ __launch_bounds__(256) void transpose_f(
    const float* __restrict__ F, float* __restrict__ FT) {
  __shared__ float t[64][65];
  const int tid = threadIdx.x;
  const int bid = blockIdx.x;                 // 256 blocks
  const int xcd = bid & 7;
  const int b   = xcd >> 1;                   // 2 XCDs per batch
  const int nt  = (bid >> 3) * 2 + (xcd & 1); // 0..63
  const float* Fb = F + (size_t)b * Cn * Nn;
  float* FTb = FT + (size_t)b * Nn * Cn;
  for (int sub = 0; sub < 4; ++sub) {
    const int nbase = nt * 256 + sub * 64;
#pragma unroll
    for (int i = 0; i < 16; ++i) {
      const int c = (tid >> 6) + 4 * i;
      t[c][tid & 63] = Fb[(size_t)c * Nn + nbase + (tid & 63)];
    }
    __syncthreads();
#pragma unroll
    for (int i = 0; i < 16; ++i) {
      const int nn = (tid >> 6) + 4 * i;
      FTb[(size_t)(nbase + nn) * Cn + (tid & 63)] = t[tid & 63][nn];
    }
    __syncthreads();
  }
}

// ---------------- kernel 1: kNN + grouped gather, 2 queries/wave ----------
// Numerics contract (bit-matches jax-GPU expected AND np reference):
//   xx  = (x*x + y*y) + z*z            (reduce, no FMA; held as h=-xx/2,
//                                       recovered via exact -2*h)
//   dot = fma(z,qz, fma(y,qy, x*qx))   (GEMM K=3 ascending-k FMA chain)
//   dist= max((xx + yy) - 2*dot, 0)    (separate elementwise ops, no FMA)
// Selection: exact top-32 by (dist, idx) via 32-bit dist keys + strict-<
// admission + monotone idx arrival (== jax.lax.top_k stable order).
// Pipeline: double-buffered LDS; next chunk's global_load_lds issued BEFORE
// the current scan, one barrier per chunk (its implicit vmcnt drain lands
// after the scan has hidden the HBM latency).
__global__ __launch_bounds__(THREADS, 4) void knn_group(
    const float* __restrict__ P,   // [B,3,N]
    const float* __restrict__ Q,   // [B,3,M]
    const float* __restrict__ FT,  // [B,N,C]
    float* __restrict__ out)       // [B,3+C,M,K]
{
#pragma clang fp contract(off)
  __shared__ float lds[2][3][CHUNK];  // double-buffered x,y,z planes (48 KiB)

  const int tid  = threadIdx.x;
  const int lane = tid & 63;
  const int wid  = tid >> 6;
  const int bid  = blockIdx.x;          // 1024
  const int xcd  = bid & 7;
  const int b    = xcd >> 1;            // 2 XCDs per batch -> L2 locality
  const int tile = (bid >> 3) * 2 + (xcd & 1);  // 0..255
  const int m0   = tile * (WPB * QPW) + wid * QPW;

  const float* Pb = P + (size_t)b * 3 * Nn;
  const float* Qb = Q + (size_t)b * 3 * Mn;

  const float2 qxv = *(const float2*)(Qb + m0);
  const float2 qyv = *(const float2*)(Qb + Mn + m0);
  const float2 qzv = *(const float2*)(Qb + 2 * Mn + m0);
  const float qx0 = qxv.x, qx1 = qxv.y;
  const float qy0 = qyv.x, qy1 = qyv.y;
  const float qz0 = qzv.x, qz1 = qzv.y;
  const float yyq0 = (qx0 * qx0 + qy0 * qy0) + qz0 * qz0;
  const float yyq1 = (qx1 * qx1 + qy1 * qy1) + qz1 * qz1;

  // selection state (per query): dist keys + parallel idx, lanes 0..31
  u32 lst_d0 = 0xFFFFFFFFu, lst_i0 = 0u, tau_d0 = 0xFFFFFFFFu;
  u32 lst_d1 = 0xFFFFFFFFu, lst_i1 = 0u, tau_d1 = 0xFFFFFFFFu;
  float tf0, tf1;

  const int base = wid * 256;                 // wave-uniform staging slice

  // ---- prologue: stage chunk 0 into buf 0 ----
  {
    const float* g0 = Pb + base + lane * 4;
    gl_lds16(g0,          &lds[0][0][base]);
    gl_lds16(g0 + Nn,     &lds[0][1][base]);
    gl_lds16(g0 + 2 * Nn, &lds[0][2][base]);
  }
  __syncthreads();

  // ---- warm start: exact top-32 of points 0..63 per query (bitonic) ----
  {
    const float x = lds[0][0][lane];
    const float y = lds[0][1][lane];
    const float z = lds[0][2][lane];
    const float xx = (x * x + y * y) + z * z;

    float dot = fmaf(z, qz0, fmaf(y, qy0, x * qx0));
    float d   = fmaxf((xx + yyq0) - 2.0f * dot, 0.0f);
    ull key = (((ull)__float_as_uint(d)) << 32) | (unsigned)lane;
    key = sort64_asc(key, lane);
    if (lane < 32) { lst_d0 = (u32)(key >> 32); lst_i0 = (u32)key; }
    tau_d0 = rdlane(lst_d0, 31);
    tf0 = tf_of(tau_d0, yyq0);

    dot = fmaf(z, qz1, fmaf(y, qy1, x * qx1));
    d   = fmaxf((xx + yyq1) - 2.0f * dot, 0.0f);
    key = (((ull)__float_as_uint(d)) << 32) | (unsigned)lane;
    key = sort64_asc(key, lane);
    if (lane < 32) { lst_d1 = (u32)(key >> 32); lst_i1 = (u32)key; }
    tau_d1 = rdlane(lst_d1, 31);
    tf1 = tf_of(tau_d1, yyq1);
  }

  // ---- main scan: stage(next) -> scan(cur) -> one barrier ----
  for (int ch = 0; ch < NCHUNK; ++ch) {
    const int cur = ch & 1;
    const int n0 = ch * CHUNK;

    if (ch + 1 < NCHUNK) {   // async: latency hides under the scan below
      const float* g0 = Pb + (ch + 1) * CHUNK + base + lane * 4;
      gl_lds16(g0,          &lds[cur ^ 1][0][base]);
      gl_lds16(g0 + Nn,     &lds[cur ^ 1][1][base]);
      gl_lds16(g0 + 2 * Nn, &lds[cur ^ 1][2][base]);
    }

#pragma unroll 2
    for (int g = 0; g < NGROUP; ++g) {
      const int p = g * 256 + lane * 4;
      const float4 rx = *(const float4*)&lds[cur][0][p];
      const float4 ry = *(const float4*)&lds[cur][1][p];
      const float4 rz = *(const float4*)&lds[cur][2][p];

      // h = -xx/2 in regs (reference xx order inside)
      float4 h;
      h.x = -0.5f * ((rx.x * rx.x + ry.x * ry.x) + rz.x * rz.x);
      h.y = -0.5f * ((rx.y * rx.y + ry.y * ry.y) + rz.y * rz.y);
      h.z = -0.5f * ((rx.z * rx.z + ry.z * ry.z) + rz.z * rz.z);
      h.w = -0.5f * ((rx.w * rx.w + ry.w * ry.w) + rz.w * rz.w);

      // surrogates for both queries: s = dot - xx/2 (3 fma each)
      float a0 = fmaf(rz.x, qz0, fmaf(ry.x, qy0, fmaf(rx.x, qx0, h.x)));
      float a1 = fmaf(rz.y, qz0, fmaf(ry.y, qy0, fmaf(rx.y, qx0, h.y)));
      float a2 = fmaf(rz.z, qz0, fmaf(ry.z, qy0, fmaf(rx.z, qx0, h.z)));
      float a3 = fmaf(rz.w, qz0, fmaf(ry.w, qy0, fmaf(rx.w, qx0, h.w)));
      float b0 = fmaf(rz.x, qz1, fmaf(ry.x, qy1, fmaf(rx.x, qx1, h.x)));
      float b1 = fmaf(rz.y, qz1, fmaf(ry.y, qy1, fmaf(rx.y, qx1, h.y)));
      float b2 = fmaf(rz.z, qz1, fmaf(ry.z, qy1, fmaf(rx.z, qx1, h.z)));
      float b3 = fmaf(rz.w, qz1, fmaf(ry.w, qy1, fmaf(rx.w, qx1, h.w)));

      // points 0..63 were consumed by the warm-start sorts
      if (ch == 0 && g == 0 && lane < 16) {
        a0 = a1 = a2 = a3 = -__builtin_inff();
        b0 = b1 = b2 = b3 = -__builtin_inff();
      }

      const float ga = fmaxf(fmaxf(a0, a1), fmaxf(a2, a3));
      const float gb = fmaxf(fmaxf(b0, b1), fmaxf(b2, b3));
      const ull mA = __ballot(ga >= tf0);
      const ull mB = __ballot(gb >= tf1);

      if (mA | mB) {
        // exact xx via -2*h (bit-exact pow2 round trip)
        const float xx0 = -2.0f * h.x;
        const float xx1 = -2.0f * h.y;
        const float xx2 = -2.0f * h.z;
        const float xx3 = -2.0f * h.w;
        const u32 sb = (u32)(n0 + g * 256);

        if (mA) {
          float dd, dv;
          u32 e0, e1, e2, e3;
          dd = fmaf(rz.x, qz0, fmaf(ry.x, qy0, rx.x * qx0));
          dv = fmaxf((xx0 + yyq0) - 2.0f * dd, 0.0f); e0 = __float_as_uint(dv);
          dd = fmaf(rz.y, qz0, fmaf(ry.y, qy0, rx.y * qx0));
          dv = fmaxf((xx1 + yyq0) - 2.0f * dd, 0.0f); e1 = __float_as_uint(dv);
          dd = fmaf(rz.z, qz0, fmaf(ry.z, qy0, rx.z * qx0));
          dv = fmaxf((xx2 + yyq0) - 2.0f * dd, 0.0f); e2 = __float_as_uint(dv);
          dd = fmaf(rz.w, qz0, fmaf(ry.w, qy0, rx.w * qx0));
          dv = fmaxf((xx3 + yyq0) - 2.0f * dd, 0.0f); e3 = __float_as_uint(dv);
          insert_grp(mA, e0, e1, e2, e3, sb, lst_d0, lst_i0, tau_d0, lane);
          tf0 = tf_of(tau_d0, yyq0);
        }
        if (mB) {
          float dd, dv;
          u32 e0, e1, e2, e3;
          dd = fmaf(rz.x, qz1, fmaf(ry.x, qy1, rx.x * qx1));
          dv = fmaxf((xx0 + yyq1) - 2.0f * dd, 0.0f); e0 = __float_as_uint(dv);
          dd = fmaf(rz.y, qz1, fmaf(ry.y, qy1, rx.y * qx1));
          dv = fmaxf((xx1 + yyq1) - 2.0f * dd, 0.0f); e1 = __float_as_uint(dv);
          dd = fmaf(rz.z, qz1, fmaf(ry.z, qy1, rx.z * qx1));
          dv = fmaxf((xx2 + yyq1) - 2.0f * dd, 0.0f); e2 = __float_as_uint(dv);
          dd = fmaf(rz.w, qz1, fmaf(ry.w, qy1, rx.w * qx1));
          dv = fmaxf((xx3 + yyq1) - 2.0f * dd, 0.0f); e3 = __float_as_uint(dv);
          insert_grp(mB, e0, e1, e2, e3, sb, lst_d1, lst_i1, tau_d1, lane);
          tf1 = tf_of(tau_d1, yyq1);
        }
      }
    }

    // single barrier per chunk: implicit vmcnt(0)+lgkmcnt(0) drain makes the
    // prefetched buffer valid for everyone and protects cur for overwrite.
    __syncthreads();
  }

  // ---- output: [B, 3+C, M, K], 2 queries per wave ----
  const size_t MK = (size_t)Mn * Kn;
  float* outb = out + (size_t)b * (3 + Cn) * MK;
  const float* FTb = FT + (size_t)b * Nn * Cn;

#pragma unroll
  for (int q = 0; q < QPW; ++q) {
    const int m = m0 + q;
    const u32 lsti = q ? lst_i1 : lst_i0;
    const float qx = q ? qx1 : qx0;
    const float qy = q ? qy1 : qy0;
    const float qz = q ? qz1 : qz0;

    if (lane < 32) {
      const int idx = (int)__shfl((int)lsti, lane);
      const float px = Pb[idx];
      const float py = Pb[Nn + idx];
      const float pz = Pb[2 * Nn + idx];
      outb[0 * MK + (size_t)m * Kn + lane] = px - qx;
      outb[1 * MK + (size_t)m * Kn + lane] = py - qy;
      outb[2 * MK + (size_t)m * Kn + lane] = pz - qz;
    }

    // features: coalesced rows from FT, 64B-segment writes
    const int r  = lane & 15;
    const int qh = lane >> 4;   // 0..3
#pragma unroll
    for (int p2 = 0; p2 < 2; ++p2) {
      const int k = p2 * 16 + r;
      const int idxk = (int)__shfl((int)lsti, k);
      const float* row = FTb + (size_t)idxk * Cn;
      float4 v[4];
#pragma unroll
      for (int i = 0; i < 4; ++i)
        v[i] = *(const float4*)(row + (qh + 4 * i) * 4);
#pragma unroll
      for (int i = 0; i < 4; ++i) {
        const int c = (qh + 4 * i) * 4;
        float* o = outb + (size_t)(3 + c) * MK + (size_t)m * Kn + k;
        o[0 * MK] = v[i].x;
        o[1 * MK] = v[i].y;
        o[2 * MK] = v[i].z;
        o[3 * MK] = v[i].w;
      }
    }
  }
}

extern "C" void kernel_launch(void* const* d_in, const int* in_sizes, int n_in,
                              void* d_out, int out_size, void* d_ws, size_t ws_size,
                              hipStream_t stream) {
  (void)in_sizes; (void)n_in; (void)out_size; (void)ws_size;
  const float* P = (const float*)d_in[0];
  const float* Q = (const float*)d_in[1];
  const float* F = (const float*)d_in[2];
  float* out = (float*)d_out;
  float* FT  = (float*)d_ws;   // 4*16384*64*4 = 16.8 MB

  hipLaunchKernelGGL(transpose_f, dim3(256), dim3(256), 0, stream, F, FT);
  hipLaunchKernelGGL(knn_group, dim3(Bn * Mn / (WPB * QPW)), dim3(THREADS), 0,
                     stream, P, Q, FT, out);
}

// Round 10
// 249.880 us; speedup vs baseline: 1.1649x; 1.1649x over previous
//
#include <hip/hip_runtime.h>

// Problem shape (fixed by setup_inputs): B=4, N=16384, M=4096, C=64, K=32
static constexpr int Bn = 4;
static constexpr int Nn = 16384;
static constexpr int Mn = 4096;
static constexpr int Cn = 64;
static constexpr int Kn = 32;

static constexpr int CHUNK   = 2048;
static constexpr int WPB     = 8;            // waves per block, 1 query/wave
static constexpr int THREADS = WPB * 64;     // 512
static constexpr int NCHUNK  = Nn / CHUNK;   // 8
static constexpr int NGROUP  = CHUNK / 256;  // 8
static constexpr int LSLOTS  = 40;           // surrogate top-LSLOTS kept

typedef unsigned long long ull;
typedef unsigned int u32;

// lane i-1 -> lane i (lane 0 keeps old). DPP wave_shr:1 — VALU pipe, no DS.
__device__ __forceinline__ u32 dpp_shr1(u32 v) {
  return (u32)__builtin_amdgcn_update_dpp((int)v, (int)v, 0x138, 0xf, 0xf, false);
}
__device__ __forceinline__ u32 rdlane(u32 v, int l) {
  return (u32)__builtin_amdgcn_readlane((int)v, l);
}
__device__ __forceinline__ float rdlane_f(float v, int l) {
  return __uint_as_float(rdlane(__float_as_uint(v), l));
}

// full-wave bitonic sort, ascending across 64 lanes (64-bit keys; one-time)
__device__ __forceinline__ ull sort64_asc(ull key, int lane) {
#pragma unroll
  for (int k = 2; k <= 64; k <<= 1) {
#pragma unroll
    for (int j = k >> 1; j > 0; j >>= 1) {
      const ull other = __shfl_xor(key, j);
      const bool keep_min = ((lane & j) == 0) == ((lane & k) == 0);
      const bool take = keep_min ? (other < key) : (other > key);
      key = take ? other : key;
    }
  }
  return key;
}

// Insert (kj surrogate, ki idx) into the DESCENDING top-40 surrogate list
// (lane j<40 holds j-th LARGEST s; lanes>=40 pinned at -inf). pos counts
// entries >= kj, so equal-s entries (earlier => lower idx) stay above: list
// order = (s desc, idx asc). ~11 wide ops, VALU only.
__device__ __forceinline__ void insert40(float kj, u32 ki,
                                         float& lst_s, u32& lst_i,
                                         float& tau_s, int lane) {
  const int pos = (int)__popcll(__ballot(lst_s >= kj));
  const float shd = __uint_as_float(dpp_shr1(__float_as_uint(lst_s)));
  const u32  shi = dpp_shr1(lst_i);
  float nd = (lane == pos) ? kj : shd;
  u32   ni = (lane == pos) ? ki : shi;
  nd = (lane < pos) ? lst_s : nd;
  ni = (lane < pos) ? lst_i : ni;
  if (lane < LSLOTS) { lst_s = nd; lst_i = ni; }
  tau_s = rdlane_f(lst_s, LSLOTS - 1);
}

// ---------------- kernel 0: F [B,C,N] -> FT [B,N,C] ----------------
__global__ __launch_bounds__(256) void transpose_f(
    const float* __restrict__ F, float* __restrict__ FT) {
  __shared__ float t[64][65];
  const int tid = threadIdx.x;
  const int bid = blockIdx.x;                 // 256 blocks
  const int xcd = bid & 7;
  const int b   = xcd >> 1;                   // 2 XCDs per batch
  const int nt  = (bid >> 3) * 2 + (xcd & 1); // 0..63
  const float* Fb = F + (size_t)b * Cn * Nn;
  float* FTb = FT + (size_t)b * Nn * Cn;
  for (int sub = 0; sub < 4; ++sub) {
    const int nbase = nt * 256 + sub * 64;
#pragma unroll
    for (int i = 0; i < 16; ++i) {
      const int c = (tid >> 6) + 4 * i;
      t[c][tid & 63] = Fb[(size_t)c * Nn + nbase + (tid & 63)];
    }
    __syncthreads();
#pragma unroll
    for (int i = 0; i < 16; ++i) {
      const int nn = (tid >> 6) + 4 * i;
      FTb[(size_t)(nbase + nn) * Cn + (tid & 63)] = t[tid & 63][nn];
    }
    __syncthreads();
  }
}

// ---------------- kernel 1: kNN + grouped gather ----------------
// Scan keeps ONLY a surrogate top-40 (s = dot - xx/2, 3 fma/pt); no exact
// math, no EPS filter in the hot loop. Final phase recomputes the exact
// reference distance for the 40 survivors and bitonic-sorts by (d, idx):
//   xx  = (x*x + y*y) + z*z            (reduce, no FMA)
//   dot = fma(z,qz, fma(y,qy, x*qx))   (GEMM K=3 ascending-k FMA chain)
//   dist= max((xx + yy) - 2*dot, 0)    (separate elementwise ops, no FMA)
// exact-top-32 subset of surrogate-top-40 holds unless >=9 rounding-scale
// (~1e-4) inversions stack inside one query's boundary — negligible.
__global__ __launch_bounds__(THREADS, 6) void knn_group(
    const float* __restrict__ P,   // [B,3,N]
    const float* __restrict__ Q,   // [B,3,M]
    const float* __restrict__ FT,  // [B,N,C]
    float* __restrict__ out)       // [B,3+C,M,K]
{
#pragma clang fp contract(off)
  __shared__ float lds[4][CHUNK];  // x, y, z, h planes (32 KiB)

  const int tid  = threadIdx.x;
  const int lane = tid & 63;
  const int wid  = tid >> 6;
  const int bid  = blockIdx.x;          // 2048
  const int xcd  = bid & 7;
  const int b    = xcd >> 1;            // 2 XCDs per batch -> L2 locality
  const int tile = (bid >> 3) * 2 + (xcd & 1);  // 0..511
  const int m    = tile * WPB + wid;

  const float* Pb = P + (size_t)b * 3 * Nn;
  const float* Qb = Q + (size_t)b * 3 * Mn;

  const float qx = Qb[m];
  const float qy = Qb[Mn + m];
  const float qz = Qb[2 * Mn + m];
  const float yyq = (qx * qx + qy * qy) + qz * qz;

  const int t4 = tid * 4;

  // selection state: descending surrogate list in lanes 0..39
  float lst_s = -__builtin_inff();
  u32   lst_i = 0u;
  float tau_s = -__builtin_inff();

  // ---- stage chunk 0 (R4-proven reg->LDS staging) ----
  {
    float4 vx = *(const float4*)(Pb + t4);
    float4 vy = *(const float4*)(Pb + Nn + t4);
    float4 vz = *(const float4*)(Pb + 2 * Nn + t4);
    float4 vh;
    vh.x = -0.5f * ((vx.x * vx.x + vy.x * vy.x) + vz.x * vz.x);
    vh.y = -0.5f * ((vx.y * vx.y + vy.y * vy.y) + vz.y * vz.y);
    vh.z = -0.5f * ((vx.z * vx.z + vy.z * vy.z) + vz.z * vz.z);
    vh.w = -0.5f * ((vx.w * vx.w + vy.w * vy.w) + vz.w * vz.w);
    *(float4*)&lds[0][t4] = vx;
    *(float4*)&lds[1][t4] = vy;
    *(float4*)&lds[2][t4] = vz;
    *(float4*)&lds[3][t4] = vh;
  }
  __syncthreads();

  // ---- warm start: exact surrogate top-40 of points 0..63 (one bitonic) ----
  {
    const float x = lds[0][lane];
    const float y = lds[1][lane];
    const float z = lds[2][lane];
    const float h = lds[3][lane];
    const float s = fmaf(z, qz, fmaf(y, qy, fmaf(x, qx, h)));
    const u32 sb = __float_as_uint(s);
    const u32 os = sb ^ (((int)sb < 0) ? 0xFFFFFFFFu : 0x80000000u);  // orderable
    ull key = (((ull)(~os)) << 32) | (u32)lane;     // asc sort => s desc, idx asc
    key = sort64_asc(key, lane);
    const int i0 = (int)(key & 0xFFFFFFFFull);
    const float sv = __shfl(s, i0);
    if (lane < LSLOTS) { lst_s = sv; lst_i = (u32)i0; }
    tau_s = rdlane_f(lst_s, LSLOTS - 1);
  }

  // ---- main scan ----
  for (int ch = 0; ch < NCHUNK; ++ch) {
    const int n0 = ch * CHUNK;

    float4 nx, ny, nz;                  // register prefetch of next chunk
    if (ch + 1 < NCHUNK) {
      nx = *(const float4*)(Pb + (n0 + CHUNK) + t4);
      ny = *(const float4*)(Pb + Nn + (n0 + CHUNK) + t4);
      nz = *(const float4*)(Pb + 2 * Nn + (n0 + CHUNK) + t4);
    }

#pragma unroll
    for (int g = 0; g < NGROUP; ++g) {
      const int p = g * 256 + lane * 4;
      const float4 rx = *(const float4*)&lds[0][p];
      const float4 ry = *(const float4*)&lds[1][p];
      const float4 rz = *(const float4*)&lds[2][p];
      const float4 rh = *(const float4*)&lds[3][p];

      // surrogate only: s = dot - xx/2 (3 fma/pt)
      float s0 = fmaf(rz.x, qz, fmaf(ry.x, qy, fmaf(rx.x, qx, rh.x)));
      float s1 = fmaf(rz.y, qz, fmaf(ry.y, qy, fmaf(rx.y, qx, rh.y)));
      float s2 = fmaf(rz.z, qz, fmaf(ry.z, qy, fmaf(rx.z, qx, rh.z)));
      float s3 = fmaf(rz.w, qz, fmaf(ry.w, qy, fmaf(rx.w, qx, rh.w)));

      if (ch == 0 && g == 0 && lane < 16) {   // 0..63 consumed by warm start
        s0 = s1 = s2 = s3 = -__builtin_inff();
      }

      const float smax = fmaxf(fmaxf(s0, s1), fmaxf(s2, s3));
      ull mm = __ballot(smax > tau_s);
      if (mm) {
        const u32 nb = (u32)(n0 + g * 256);
        do {
          const int src = (int)__builtin_ctzll(mm);
          mm &= mm - 1;
          const u32 ib = nb + ((u32)src << 2);
          float k;
          k = rdlane_f(s0, src);
          if (k > tau_s) insert40(k, ib + 0u, lst_s, lst_i, tau_s, lane);
          k = rdlane_f(s1, src);
          if (k > tau_s) insert40(k, ib + 1u, lst_s, lst_i, tau_s, lane);
          k = rdlane_f(s2, src);
          if (k > tau_s) insert40(k, ib + 2u, lst_s, lst_i, tau_s, lane);
          k = rdlane_f(s3, src);
          if (k > tau_s) insert40(k, ib + 3u, lst_s, lst_i, tau_s, lane);
        } while (mm);
      }
    }
    __syncthreads();

    if (ch + 1 < NCHUNK) {
      float4 vh;
      vh.x = -0.5f * ((nx.x * nx.x + ny.x * ny.x) + nz.x * nz.x);
      vh.y = -0.5f * ((nx.y * nx.y + ny.y * ny.y) + nz.y * nz.y);
      vh.z = -0.5f * ((nx.z * nx.z + ny.z * ny.z) + nz.z * nz.z);
      vh.w = -0.5f * ((nx.w * nx.w + ny.w * ny.w) + nz.w * nz.w);
      *(float4*)&lds[0][t4] = nx;
      *(float4*)&lds[1][t4] = ny;
      *(float4*)&lds[2][t4] = nz;
      *(float4*)&lds[3][t4] = vh;
      __syncthreads();
    }
  }

  // ---- final: exact reference distance for the 40 survivors, sort, take 32 --
  ull key;
  {
    const int idx = (int)lst_i;               // lanes>=40: 0 (harmless load)
    const float x = Pb[idx];
    const float y = Pb[Nn + idx];
    const float z = Pb[2 * Nn + idx];
    const float xx = (x * x + y * y) + z * z;              // reference order
    const float dot = fmaf(z, qz, fmaf(y, qy, x * qx));    // asc-k FMA chain
    const float d = fmaxf((xx + yyq) - 2.0f * dot, 0.0f);  // no contraction
    key = (lane < LSLOTS)
            ? ((((ull)__float_as_uint(d)) << 32) | (u32)idx)
            : ~0ull;
    key = sort64_asc(key, lane);              // (d asc, idx asc); top-32 in 0..31
  }

  // ---- output: [B, 3+C, M, K] ----
  const size_t MK = (size_t)Mn * Kn;
  float* outb = out + (size_t)b * (3 + Cn) * MK;

  if (lane < 32) {
    const int idx = (int)(key & 0xFFFFFFFFull);
    const float px = Pb[idx];
    const float py = Pb[Nn + idx];
    const float pz = Pb[2 * Nn + idx];
    outb[0 * MK + (size_t)m * Kn + lane] = px - qx;
    outb[1 * MK + (size_t)m * Kn + lane] = py - qy;
    outb[2 * MK + (size_t)m * Kn + lane] = pz - qz;
  }

  // features: coalesced rows from FT, 64B-segment writes
  const float* FTb = FT + (size_t)b * Nn * Cn;
  const int r  = lane & 15;
  const int qh = lane >> 4;   // 0..3
#pragma unroll
  for (int p2 = 0; p2 < 2; ++p2) {
    const int k = p2 * 16 + r;
    const int idxk = (int)(__shfl(key, k) & 0xFFFFFFFFull);
    const float* row = FTb + (size_t)idxk * Cn;
    float4 v[4];
#pragma unroll
    for (int i = 0; i < 4; ++i)
      v[i] = *(const float4*)(row + (qh + 4 * i) * 4);
#pragma unroll
    for (int i = 0; i < 4; ++i) {
      const int c = (qh + 4 * i) * 4;
      float* o = outb + (size_t)(3 + c) * MK + (size_t)m * Kn + k;
      o[0 * MK] = v[i].x;
      o[1 * MK] = v[i].y;
      o[2 * MK] = v[i].z;
      o[3 * MK] = v[i].w;
    }
  }
}

extern "C" void kernel_launch(void* const* d_in, const int* in_sizes, int n_in,
                              void* d_out, int out_size, void* d_ws, size_t ws_size,
                              hipStream_t stream) {
  (void)in_sizes; (void)n_in; (void)out_size; (void)ws_size;
  const float* P = (const float*)d_in[0];
  const float* Q = (const float*)d_in[1];
  const float* F = (const float*)d_in[2];
  float* out = (float*)d_out;
  float* FT  = (float*)d_ws;   // 4*16384*64*4 = 16.8 MB

  hipLaunchKernelGGL(transpose_f, dim3(256), dim3(256), 0, stream, F, FT);
  hipLaunchKernelGGL(knn_group, dim3(Bn * Mn / WPB), dim3(THREADS), 0, stream,
                     P, Q, FT, out);
}

// Round 11
// 188.541 us; speedup vs baseline: 1.5439x; 1.3253x over previous
//
#include <hip/hip_runtime.h>

// Problem shape (fixed by setup_inputs): B=4, N=16384, M=4096, C=64, K=32
static constexpr int Bn = 4;
static constexpr int Nn = 16384;
static constexpr int Mn = 4096;
static constexpr int Cn = 64;
static constexpr int Kn = 32;

static constexpr int CHUNK   = 2048;
static constexpr int WPB     = 8;            // waves per block, 1 query/wave
static constexpr int THREADS = WPB * 64;     // 512
static constexpr int NCHUNK  = Nn / CHUNK;   // 8
static constexpr int NGROUP  = CHUNK / 256;  // 8
static constexpr int LSLOTS  = 40;           // surrogate top-LSLOTS kept

typedef unsigned long long ull;
typedef unsigned int u32;

// lane i-1 -> lane i (lane 0 keeps old). DPP wave_shr:1 — VALU pipe, no DS.
__device__ __forceinline__ u32 dpp_shr1(u32 v) {
  return (u32)__builtin_amdgcn_update_dpp((int)v, (int)v, 0x138, 0xf, 0xf, false);
}
__device__ __forceinline__ u32 rdlane(u32 v, int l) {
  return (u32)__builtin_amdgcn_readlane((int)v, l);
}
__device__ __forceinline__ float rdlane_f(float v, int l) {
  return __uint_as_float(rdlane(__float_as_uint(v), l));
}

// full-wave bitonic sort, ascending across 64 lanes (64-bit keys; one-time)
__device__ __forceinline__ ull sort64_asc(ull key, int lane) {
#pragma unroll
  for (int k = 2; k <= 64; k <<= 1) {
#pragma unroll
    for (int j = k >> 1; j > 0; j >>= 1) {
      const ull other = __shfl_xor(key, j);
      const bool keep_min = ((lane & j) == 0) == ((lane & k) == 0);
      const bool take = keep_min ? (other < key) : (other > key);
      key = take ? other : key;
    }
  }
  return key;
}

// Insert (kj surrogate, ki idx) into the DESCENDING top-40 surrogate list
// (lane j<40 holds j-th LARGEST s; lanes>=40 pinned at -inf). pos counts
// entries >= kj, so equal-s entries stay above. ~10 wide ops, VALU only.
__device__ __forceinline__ void insert40(float kj, u32 ki,
                                         float& lst_s, u32& lst_i,
                                         float& tau_s, int lane) {
  const int pos = (int)__popcll(__ballot(lst_s >= kj));
  const float shd = __uint_as_float(dpp_shr1(__float_as_uint(lst_s)));
  const u32  shi = dpp_shr1(lst_i);
  float nd = (lane == pos) ? kj : shd;
  u32   ni = (lane == pos) ? ki : shi;
  nd = (lane < pos) ? lst_s : nd;
  ni = (lane < pos) ? lst_i : ni;
  if (lane < LSLOTS) { lst_s = nd; lst_i = ni; }
  tau_s = rdlane_f(lst_s, LSLOTS - 1);
}

// Per-subword candidate loop, R4-style: iterate only actual candidates,
// re-prune the mask after every insert (tau tightened => lanes drop out
// with ZERO loop iterations).
#define SUBW_INS(SX, JOFF)                                                   \
  {                                                                          \
    ull mm = __ballot((SX) > tau_s);                                         \
    while (mm) {                                                             \
      const int src = (int)__builtin_ctzll(mm);                              \
      const float k = rdlane_f((SX), src);                                   \
      if (k > tau_s)                                                         \
        insert40(k, nb + ((u32)src << 2) + (JOFF), lst_s, lst_i, tau_s, lane);\
      mm &= mm - 1;                                                          \
      mm &= __ballot((SX) > tau_s);                                          \
    }                                                                        \
  }

// ---------------- kernel 0: F [B,C,N] -> FT [B,N,C] ----------------
__global__ __launch_bounds__(256) void transpose_f(
    const float* __restrict__ F, float* __restrict__ FT) {
  __shared__ float t[64][65];
  const int tid = threadIdx.x;
  const int bid = blockIdx.x;                 // 256 blocks
  const int xcd = bid & 7;
  const int b   = xcd >> 1;                   // 2 XCDs per batch
  const int nt  = (bid >> 3) * 2 + (xcd & 1); // 0..63
  const float* Fb = F + (size_t)b * Cn * Nn;
  float* FTb = FT + (size_t)b * Nn * Cn;
  for (int sub = 0; sub < 4; ++sub) {
    const int nbase = nt * 256 + sub * 64;
#pragma unroll
    for (int i = 0; i < 16; ++i) {
      const int c = (tid >> 6) + 4 * i;
      t[c][tid & 63] = Fb[(size_t)c * Nn + nbase + (tid & 63)];
    }
    __syncthreads();
#pragma unroll
    for (int i = 0; i < 16; ++i) {
      const int nn = (tid >> 6) + 4 * i;
      FTb[(size_t)(nbase + nn) * Cn + (tid & 63)] = t[tid & 63][nn];
    }
    __syncthreads();
  }
}

// ---------------- kernel 1: kNN + grouped gather ----------------
// Hot loop keeps ONLY a surrogate top-40 (s = dot - xx/2, 3 fma/pt). Final
// phase recomputes the exact reference distance for the 40 survivors and
// bitonic-sorts by (d, idx):
//   xx  = (x*x + y*y) + z*z            (reduce, no FMA)
//   dot = fma(z,qz, fma(y,qy, x*qx))   (GEMM K=3 ascending-k FMA chain)
//   dist= max((xx + yy) - 2*dot, 0)    (separate elementwise ops, no FMA)
// exact-top-32 subset of surrogate-top-40: needs >=9 rounding-scale (~1e-4)
// inversions stacked inside one query's boundary — negligible.
__global__ __launch_bounds__(THREADS, 6) void knn_group(
    const float* __restrict__ P,   // [B,3,N]
    const float* __restrict__ Q,   // [B,3,M]
    const float* __restrict__ FT,  // [B,N,C]
    float* __restrict__ out)       // [B,3+C,M,K]
{
#pragma clang fp contract(off)
  __shared__ float lds[4][CHUNK];  // x, y, z, h planes (32 KiB)

  const int tid  = threadIdx.x;
  const int lane = tid & 63;
  const int wid  = tid >> 6;
  const int bid  = blockIdx.x;          // 2048
  const int xcd  = bid & 7;
  const int b    = xcd >> 1;            // 2 XCDs per batch -> L2 locality
  const int tile = (bid >> 3) * 2 + (xcd & 1);  // 0..511
  const int m    = tile * WPB + wid;

  const float* Pb = P + (size_t)b * 3 * Nn;
  const float* Qb = Q + (size_t)b * 3 * Mn;

  const float qx = Qb[m];
  const float qy = Qb[Mn + m];
  const float qz = Qb[2 * Mn + m];
  const float yyq = (qx * qx + qy * qy) + qz * qz;

  const int t4 = tid * 4;

  // selection state: descending surrogate list in lanes 0..39
  float lst_s = -__builtin_inff();
  u32   lst_i = 0u;
  float tau_s = -__builtin_inff();

  // ---- stage chunk 0 (R4-proven reg->LDS staging) ----
  {
    float4 vx = *(const float4*)(Pb + t4);
    float4 vy = *(const float4*)(Pb + Nn + t4);
    float4 vz = *(const float4*)(Pb + 2 * Nn + t4);
    float4 vh;
    vh.x = -0.5f * ((vx.x * vx.x + vy.x * vy.x) + vz.x * vz.x);
    vh.y = -0.5f * ((vx.y * vx.y + vy.y * vy.y) + vz.y * vz.y);
    vh.z = -0.5f * ((vx.z * vx.z + vy.z * vy.z) + vz.z * vz.z);
    vh.w = -0.5f * ((vx.w * vx.w + vy.w * vy.w) + vz.w * vz.w);
    *(float4*)&lds[0][t4] = vx;
    *(float4*)&lds[1][t4] = vy;
    *(float4*)&lds[2][t4] = vz;
    *(float4*)&lds[3][t4] = vh;
  }
  __syncthreads();

  // ---- warm start: surrogate top-40 of points 0..63 (one bitonic sort) ----
  {
    const float x = lds[0][lane];
    const float y = lds[1][lane];
    const float z = lds[2][lane];
    const float h = lds[3][lane];
    const float s = fmaf(z, qz, fmaf(y, qy, fmaf(x, qx, h)));
    const u32 sb = __float_as_uint(s);
    const u32 os = sb ^ (((int)sb < 0) ? 0xFFFFFFFFu : 0x80000000u);  // orderable
    ull key = (((ull)(~os)) << 32) | (u32)lane;     // asc sort => s desc, idx asc
    key = sort64_asc(key, lane);
    const int i0 = (int)(key & 0xFFFFFFFFull);
    const float sv = __shfl(s, i0);
    if (lane < LSLOTS) { lst_s = sv; lst_i = (u32)i0; }
    tau_s = rdlane_f(lst_s, LSLOTS - 1);
  }

  // ---- main scan ----
  for (int ch = 0; ch < NCHUNK; ++ch) {
    const int n0 = ch * CHUNK;

    float4 nx, ny, nz;                  // register prefetch of next chunk
    if (ch + 1 < NCHUNK) {
      nx = *(const float4*)(Pb + (n0 + CHUNK) + t4);
      ny = *(const float4*)(Pb + Nn + (n0 + CHUNK) + t4);
      nz = *(const float4*)(Pb + 2 * Nn + (n0 + CHUNK) + t4);
    }

#pragma unroll
    for (int g = 0; g < NGROUP; ++g) {
      const int p = g * 256 + lane * 4;
      const float4 rx = *(const float4*)&lds[0][p];
      const float4 ry = *(const float4*)&lds[1][p];
      const float4 rz = *(const float4*)&lds[2][p];
      const float4 rh = *(const float4*)&lds[3][p];

      // surrogate only: s = dot - xx/2 (3 fma/pt)
      float s0 = fmaf(rz.x, qz, fmaf(ry.x, qy, fmaf(rx.x, qx, rh.x)));
      float s1 = fmaf(rz.y, qz, fmaf(ry.y, qy, fmaf(rx.y, qx, rh.y)));
      float s2 = fmaf(rz.z, qz, fmaf(ry.z, qy, fmaf(rx.z, qx, rh.z)));
      float s3 = fmaf(rz.w, qz, fmaf(ry.w, qy, fmaf(rx.w, qx, rh.w)));

      if (ch == 0 && g == 0 && lane < 16) {   // 0..63 consumed by warm start
        s0 = s1 = s2 = s3 = -__builtin_inff();
      }

      const float smax = fmaxf(fmaxf(s0, s1), fmaxf(s2, s3));
      if (__any(smax > tau_s)) {
        const u32 nb = (u32)(n0 + g * 256);
        SUBW_INS(s0, 0u)
        SUBW_INS(s1, 1u)
        SUBW_INS(s2, 2u)
        SUBW_INS(s3, 3u)
      }
    }
    __syncthreads();

    if (ch + 1 < NCHUNK) {
      float4 vh;
      vh.x = -0.5f * ((nx.x * nx.x + ny.x * ny.x) + nz.x * nz.x);
      vh.y = -0.5f * ((nx.y * nx.y + ny.y * ny.y) + nz.y * nz.y);
      vh.z = -0.5f * ((nx.z * nx.z + ny.z * ny.z) + nz.z * nz.z);
      vh.w = -0.5f * ((nx.w * nx.w + ny.w * ny.w) + nz.w * nz.w);
      *(float4*)&lds[0][t4] = nx;
      *(float4*)&lds[1][t4] = ny;
      *(float4*)&lds[2][t4] = nz;
      *(float4*)&lds[3][t4] = vh;
      __syncthreads();
    }
  }

  // ---- final: exact reference distance for the 40 survivors, sort, take 32 --
  ull key;
  {
    const int idx = (int)lst_i;               // lanes>=40: 0 (harmless load)
    const float x = Pb[idx];
    const float y = Pb[Nn + idx];
    const float z = Pb[2 * Nn + idx];
    const float xx = (x * x + y * y) + z * z;              // reference order
    const float dot = fmaf(z, qz, fmaf(y, qy, x * qx));    // asc-k FMA chain
    const float d = fmaxf((xx + yyq) - 2.0f * dot, 0.0f);  // no contraction
    key = (lane < LSLOTS)
            ? ((((ull)__float_as_uint(d)) << 32) | (u32)idx)
            : ~0ull;
    key = sort64_asc(key, lane);              // (d asc, idx asc); top-32 in 0..31
  }

  // ---- output: [B, 3+C, M, K] ----
  const size_t MK = (size_t)Mn * Kn;
  float* outb = out + (size_t)b * (3 + Cn) * MK;

  if (lane < 32) {
    const int idx = (int)(key & 0xFFFFFFFFull);
    const float px = Pb[idx];
    const float py = Pb[Nn + idx];
    const float pz = Pb[2 * Nn + idx];
    outb[0 * MK + (size_t)m * Kn + lane] = px - qx;
    outb[1 * MK + (size_t)m * Kn + lane] = py - qy;
    outb[2 * MK + (size_t)m * Kn + lane] = pz - qz;
  }

  // features: coalesced rows from FT, 64B-segment writes
  const float* FTb = FT + (size_t)b * Nn * Cn;
  const int r  = lane & 15;
  const int qh = lane >> 4;   // 0..3
#pragma unroll
  for (int p2 = 0; p2 < 2; ++p2) {
    const int k = p2 * 16 + r;
    const int idxk = (int)(__shfl(key, k) & 0xFFFFFFFFull);
    const float* row = FTb + (size_t)idxk * Cn;
    float4 v[4];
#pragma unroll
    for (int i = 0; i < 4; ++i)
      v[i] = *(const float4*)(row + (qh + 4 * i) * 4);
#pragma unroll
    for (int i = 0; i < 4; ++i) {
      const int c = (qh + 4 * i) * 4;
      float* o = outb + (size_t)(3 + c) * MK + (size_t)m * Kn + k;
      o[0 * MK] = v[i].x;
      o[1 * MK] = v[i].y;
      o[2 * MK] = v[i].z;
      o[3 * MK] = v[i].w;
    }
  }
}

extern "C" void kernel_launch(void* const* d_in, const int* in_sizes, int n_in,
                              void* d_out, int out_size, void* d_ws, size_t ws_size,
                              hipStream_t stream) {
  (void)in_sizes; (void)n_in; (void)out_size; (void)ws_size;
  const float* P = (const float*)d_in[0];
  const float* Q = (const float*)d_in[1];
  const float* F = (const float*)d_in[2];
  float* out = (float*)d_out;
  float* FT  = (float*)d_ws;   // 4*16384*64*4 = 16.8 MB

  hipLaunchKernelGGL(transpose_f, dim3(256), dim3(256), 0, stream, F, FT);
  hipLaunchKernelGGL(knn_group, dim3(Bn * Mn / WPB), dim3(THREADS), 0, stream,
                     P, Q, FT, out);
}